// Round 9
// baseline (178.545 us; speedup 1.0000x reference)
//
#include <hip/hip_runtime.h>
#include <hip/hip_bf16.h>

#define NN  4
#define CIN 96
#define C1  128
#define C2  144
#define HH  128
#define WW  256
#define NPX ((size_t)NN * HH * WW)          // pixels per chunk-plane (131072)

typedef short bf16x8 __attribute__((ext_vector_type(8)));
typedef float f32x4  __attribute__((ext_vector_type(4)));
typedef unsigned int u32x4 __attribute__((ext_vector_type(4)));

__device__ __forceinline__ short f2bs(float v) {
    __hip_bfloat16 b = __float2bfloat16(v);
    short s; __builtin_memcpy(&s, &b, 2); return s;
}

// async global->LDS, 16B per lane. LDS dest linear (base + lane*16).
__device__ __forceinline__ void gld16(const void* g, void* l) {
    __builtin_amdgcn_global_load_lds(
        (const __attribute__((address_space(1))) void*)g,
        (__attribute__((address_space(3))) void*)l, 16, 0, 0);
}

// ---------------------------------------------------------------------------
// Fused prolog: blocks [0,512) transpose feat NCHW fp32 -> chunk-major bf16
// featT[kc][n][h][w][32]; blocks [512,944) pack w1; blocks [944,1592) pack w2.
__global__ __launch_bounds__(256) void prolog(
    const float* __restrict__ feat, short* __restrict__ featT,
    short* __restrict__ zbuf,
    const float* __restrict__ w1, short* __restrict__ w1p,
    const float* __restrict__ w2, short* __restrict__ w2p)
{
    __shared__ unsigned int lds[48 * 258];        // 49.5 KB (transpose blocks only)
    const int b   = blockIdx.x;
    const int tid = threadIdx.x;

    if (b < 512) {                                // ---- transpose ----
        const int h = b & (HH - 1);
        const int n = b >> 7;
        if (b == 0 && tid < 32) zbuf[tid] = 0;

        #pragma unroll 4
        for (int cp = 0; cp < 48; ++cp) {         // channel pairs
            float v0 = feat[(((size_t)n * CIN + 2 * cp    ) * HH + h) * WW + tid];
            float v1 = feat[(((size_t)n * CIN + 2 * cp + 1) * HH + h) * WW + tid];
            unsigned int p = (unsigned int)(unsigned short)f2bs(v0)
                           | ((unsigned int)(unsigned short)f2bs(v1) << 16);
            lds[cp * 258 + tid] = p;
        }
        __syncthreads();
        const size_t rowbase = (size_t)(n * HH + h) * WW * 32;
        #pragma unroll
        for (int kc = 0; kc < 3; ++kc) {
            short* dst = featT + (size_t)kc * (NPX * 32) + rowbase;
            #pragma unroll
            for (int it = 0; it < 4; ++it) {
                const int slot = it * 256 + tid;
                const int px = slot >> 2, sub = slot & 3;
                u32x4 v;                           // ci pairs kc*16+sub*4+k
                #pragma unroll
                for (int k = 0; k < 4; ++k)
                    v[k] = lds[(kc * 16 + sub * 4 + k) * 258 + px];
                *(u32x4*)&dst[(size_t)slot * 8] = v;
            }
        }
        return;
    }

    // ---- weight packs: wp[(((kci*9+tap)*nct+ct)*64+lane)*8+j] ----
    const float* w; short* wp; int cin, nct, i;
    if (b < 944) { w = w1; wp = w1p; cin = CIN; nct = 8; i = (b - 512) * 256 + tid; }
    else         { w = w2; wp = w2p; cin = C1;  nct = 9; i = (b - 944) * 256 + tid; }
    const int j    = i & 7;
    const int col  = (i >> 3) & 15;
    const int quad = (i >> 7) & 3;
    int t = i >> 9;                               // (kci*9+tap)*nct + ct
    const int ct  = t % nct;  t /= nct;
    const int tap = t % 9;
    const int kci = t / 9;
    const int co = ct * 16 + col;
    const int ci = kci * 32 + quad * 8 + j;
    wp[i] = f2bs(w[((size_t)co * cin + ci) * 9 + tap]);
}

// ---------------------------------------------------------------------------
// conv1, counted-vmcnt schedule (T4): 27 per-tap phases, B TRIPLE-buffered
// (3 x 8.2 KB). Phase q: {compute(q); [boundary: barrier + stageA]; issue
// stageB(q+2); s_waitcnt vmcnt(2) (leaves q+2 in flight, drains q+1);
// raw s_barrier}. Loads are never drained to 0 in the loop. Buffer safety:
// stage(q+3) is issued only after barrier(q), whose precondition is all
// waves finished compute(q) = last reader of that buffer.
// Per-wave gld16 counts: stageB = 2 (uniform); stageA = 13 (w0) / 12.
__global__ __launch_bounds__(256, 2) void conv1_mfma(
    const short* __restrict__ featT, const short* __restrict__ w1p,
    const float* __restrict__ b1, short* __restrict__ hfeat,
    const short* __restrict__ zbuf)
{
    __shared__ __attribute__((aligned(16))) short ldsA[3 * 258 * 32]; // 49,536 B
    __shared__ __attribute__((aligned(16))) short ldsB[3][8 * 512];   // 24,576 B
    const int tid  = threadIdx.x;
    const int bid  = ((blockIdx.x & 7) << 6) + (blockIdx.x >> 3); // 512 = 8x64
    const int h    = bid & (HH - 1);
    const int n    = bid >> 7;
    const int lane = tid & 63, wave = tid >> 6;
    const int quad = lane >> 4, col = lane & 15;
    const int wp0  = wave * 64;

    f32x4 acc[4][8];
    #pragma unroll
    for (int mt = 0; mt < 4; ++mt)
        #pragma unroll
        for (int ct = 0; ct < 8; ++ct)
            #pragma unroll
            for (int r = 0; r < 4; ++r) acc[mt][ct][r] = 0.f;

    auto stageA = [&](int kci) {
        const short* cbase = featT + (size_t)kci * (NPX * 32);
        for (int s = tid; s < 3 * 258 * 4; s += 256) {
            const int cig = s & 3;
            const int px  = (s >> 2) % 258;
            const int row = (s >> 2) / 258;
            const int hh = h + row - 1, gw = px - 1;
            const short* g = zbuf;
            if (hh >= 0 && hh < HH && gw >= 0 && gw < WW)
                g = cbase + ((size_t)(n * HH + hh) * WW + gw) * 32
                    + ((cig ^ ((px >> 1) & 3)) << 3);   // source pre-swizzle
            gld16(g, &ldsA[s * 8]);
        }
    };
    auto stageB = [&](int q, int buf) {           // one tap: 512 x 16B
        const short* gB = w1p + (size_t)q * 4096;
        #pragma unroll
        for (int t = 0; t < 2; ++t)
            gld16(gB + (t * 256 + tid) * 8, &ldsB[buf][(t * 256 + tid) * 8]);
    };
    auto compute = [&](int q) {
        const int tap = q % 9, dh = tap / 3, dw = tap % 3;
        const short* Bbuf = ldsB[q % 3];
        __builtin_amdgcn_s_setprio(1);
        bf16x8 af[4];
        #pragma unroll
        for (int mt = 0; mt < 4; ++mt) {
            const int px = wp0 + mt * 16 + col + dw;
            const int slot = (dh * 258 + px) * 4 + (quad ^ ((px >> 1) & 3));
            af[mt] = *(const bf16x8*)&ldsA[slot * 8];
        }
        #pragma unroll
        for (int ct = 0; ct < 8; ++ct) {
            const bf16x8 bfr = *(const bf16x8*)&Bbuf[(ct << 9) + (lane << 3)];
            #pragma unroll
            for (int mt = 0; mt < 4; ++mt)
                acc[mt][ct] = __builtin_amdgcn_mfma_f32_16x16x32_bf16(af[mt], bfr, acc[mt][ct], 0, 0, 0);
        }
        __builtin_amdgcn_s_setprio(0);
    };

    // prologue: A0, B0, B1 in flight; wait A0+B0 (leave B1's 2 outstanding)
    stageA(0);
    stageB(0, 0);
    stageB(1, 1);
    __builtin_amdgcn_sched_barrier(0);
    asm volatile("s_waitcnt vmcnt(2)" ::: "memory");
    __builtin_amdgcn_s_barrier();
    __builtin_amdgcn_sched_barrier(0);

    for (int q = 0; q < 27; ++q) {
        compute(q);
        if (q == 26) break;
        __builtin_amdgcn_sched_barrier(0);
        if (q % 9 == 8) {                         // next compute uses new A
            __builtin_amdgcn_s_barrier();         // all done reading A
            stageA(q / 9 + 1);
        }
        if (q + 2 <= 26) stageB(q + 2, (q + 2) % 3);
        __builtin_amdgcn_sched_barrier(0);
        if (q + 2 <= 26) asm volatile("s_waitcnt vmcnt(2)" ::: "memory");
        else             asm volatile("s_waitcnt vmcnt(0)" ::: "memory");
        __builtin_amdgcn_s_barrier();
        __builtin_amdgcn_sched_barrier(0);
    }

    float bias[8];
    #pragma unroll
    for (int ct = 0; ct < 8; ++ct) bias[ct] = b1[ct * 16 + col];
    #pragma unroll
    for (int mt = 0; mt < 4; ++mt)
        #pragma unroll
        for (int r = 0; r < 4; ++r) {
            const int w = wp0 + mt * 16 + quad * 4 + r;
            const size_t pxw = (size_t)(n * HH + h) * WW + w;
            #pragma unroll
            for (int ct = 0; ct < 8; ++ct) {
                float a = acc[mt][ct][r] + bias[ct];
                a = a > 0.f ? a : 0.1f * a;       // LeakyReLU(0.1)
                hfeat[((size_t)(ct >> 1) * NPX + pxw) * 32 + (ct & 1) * 16 + col] = f2bs(a);
            }
        }
}

// ---------------------------------------------------------------------------
// conv2 + fused epilogue, counted-vmcnt schedule: 36 per-tap phases, B
// triple-buffered (3 x 9.2 KB; LDS total 77.2 KB -> 2 blocks/CU).
// Per-wave gld16 counts: stageB = 3 (wave 0) / 2; stageA = 13 (w0) / 12.
// vmcnt N = own-wave stageB count (leaves stage(q+2) in flight).
__global__ __launch_bounds__(256, 2) void conv2_fused(
    const short* __restrict__ hfeat, const short* __restrict__ w2p,
    const float* __restrict__ b2, const float* __restrict__ flow,
    float* __restrict__ out, const short* __restrict__ zbuf)
{
    __shared__ __attribute__((aligned(16))) short ldsA[3 * 258 * 32]; // 49,536 B
    __shared__ __attribute__((aligned(16))) short ldsB[3][9 * 512];   // 27,648 B
    const int tid  = threadIdx.x;
    const int bid  = ((blockIdx.x & 7) << 6) + (blockIdx.x >> 3);
    const int h    = bid & (HH - 1);
    const int n    = bid >> 7;
    const int lane = tid & 63, wave = tid >> 6;
    const int quad = lane >> 4, col = lane & 15;
    const int wp0  = wave * 64;

    f32x4 acc[4][9];
    #pragma unroll
    for (int mt = 0; mt < 4; ++mt)
        #pragma unroll
        for (int ct = 0; ct < 9; ++ct)
            #pragma unroll
            for (int r = 0; r < 4; ++r) acc[mt][ct][r] = 0.f;

    auto stageA = [&](int kci) {
        const short* cbase = hfeat + (size_t)kci * (NPX * 32);
        for (int s = tid; s < 3 * 258 * 4; s += 256) {
            const int cig = s & 3;
            const int px  = (s >> 2) % 258;
            const int row = (s >> 2) / 258;
            const int hh = h + row - 1, gw = px - 1;
            const short* g = zbuf;
            if (hh >= 0 && hh < HH && gw >= 0 && gw < WW)
                g = cbase + ((size_t)(n * HH + hh) * WW + gw) * 32
                    + ((cig ^ ((px >> 1) & 3)) << 3);
            gld16(g, &ldsA[s * 8]);
        }
    };
    auto stageB = [&](int q, int buf) {           // one tap: 576 x 16B
        const short* gB = w2p + (size_t)q * 4608;
        for (int t = tid; t < 576; t += 256)      // wave0: 3 instr, others: 2
            gld16(gB + t * 8, &ldsB[buf][t * 8]);
    };
    auto waitB = [&](void) {                      // leave own-wave stage(q+2)
        if (wave == 0) asm volatile("s_waitcnt vmcnt(3)" ::: "memory");
        else           asm volatile("s_waitcnt vmcnt(2)" ::: "memory");
    };
    auto compute = [&](int q) {
        const int tap = q % 9, dh = tap / 3, dw = tap % 3;
        const short* Bbuf = ldsB[q % 3];
        __builtin_amdgcn_s_setprio(1);
        bf16x8 af[4];
        #pragma unroll
        for (int mt = 0; mt < 4; ++mt) {
            const int px = wp0 + mt * 16 + col + dw;
            const int slot = (dh * 258 + px) * 4 + (quad ^ ((px >> 1) & 3));
            af[mt] = *(const bf16x8*)&ldsA[slot * 8];
        }
        #pragma unroll
        for (int ct = 0; ct < 9; ++ct) {
            const bf16x8 bfr = *(const bf16x8*)&Bbuf[(ct << 9) + (lane << 3)];
            #pragma unroll
            for (int mt = 0; mt < 4; ++mt)
                acc[mt][ct] = __builtin_amdgcn_mfma_f32_16x16x32_bf16(af[mt], bfr, acc[mt][ct], 0, 0, 0);
        }
        __builtin_amdgcn_s_setprio(0);
    };

    stageA(0);
    stageB(0, 0);
    stageB(1, 1);
    __builtin_amdgcn_sched_barrier(0);
    waitB();
    __builtin_amdgcn_s_barrier();
    __builtin_amdgcn_sched_barrier(0);

    for (int q = 0; q < 36; ++q) {
        compute(q);
        if (q == 35) break;
        __builtin_amdgcn_sched_barrier(0);
        if (q % 9 == 8) {                         // next compute uses new A
            __builtin_amdgcn_s_barrier();         // all done reading A
            stageA(q / 9 + 1);
        }
        if (q + 2 <= 35) stageB(q + 2, (q + 2) % 3);
        __builtin_amdgcn_sched_barrier(0);
        if (q + 2 <= 35) waitB();
        else             asm volatile("s_waitcnt vmcnt(0)" ::: "memory");
        __builtin_amdgcn_s_barrier();
        __builtin_amdgcn_sched_barrier(0);
    }
    __syncthreads();                              // epilogue boundary

    // ---- epilogue: ldsA reused as out-stage [2][4][1028] + flow cache ----
    float* outs = (float*)ldsA;                   // 32,896 B
    float* flds = (float*)ldsA + 8224;            // [2][3][264], 6,336 B
    for (int i = tid; i < 2 * 3 * 258; i += 256) {
        const int px = i % 258;
        const int t  = i / 258;
        const int row = t % 3, c = t / 3;
        const int hh = h + row - 1, gw = px - 1;
        float v = 0.f;
        if (hh >= 0 && hh < HH && gw >= 0 && gw < WW)
            v = flow[(((size_t)n * 2 + c) * HH + hh) * WW + gw];
        flds[(c * 3 + row) * 264 + px] = v;
    }
    __syncthreads();

    const int a_ = col >> 2, b_ = col & 3;
    float bias[9];
    #pragma unroll
    for (int k = 0; k < 9; ++k) bias[k] = b2[k * 16 + col];

    #pragma unroll
    for (int mt = 0; mt < 4; ++mt) {
        const int w0 = wp0 + mt * 16 + quad * 4;
        float fw[2][3][6];                        // flow window w0-1 .. w0+4
        #pragma unroll
        for (int c = 0; c < 2; ++c)
            #pragma unroll
            for (int ki = 0; ki < 3; ++ki)
                #pragma unroll
                for (int j = 0; j < 6; ++j)
                    fw[c][ki][j] = flds[(c * 3 + ki) * 264 + w0 + j];
        #pragma unroll
        for (int r = 0; r < 4; ++r) {
            const int w = w0 + r;
            float v[9], mx = -1e30f;
            #pragma unroll
            for (int k = 0; k < 9; ++k) {
                v[k] = 0.25f * (acc[mt][k][r] + bias[k]);
                mx = fmaxf(mx, v[k]);
            }
            float s = 0.f;
            #pragma unroll
            for (int k = 0; k < 9; ++k) { v[k] = __expf(v[k] - mx); s += v[k]; }
            const float inv = 4.f / s;            // folds the 4*flow scale
            float o0 = 0.f, o1 = 0.f;
            #pragma unroll
            for (int ki = 0; ki < 3; ++ki)
                #pragma unroll
                for (int kj = 0; kj < 3; ++kj) {
                    const float wgt = v[ki * 3 + kj];
                    o0 += wgt * fw[0][ki][r + kj];
                    o1 += wgt * fw[1][ki][r + kj];
                }
            outs[(0 * 4 + a_) * 1028 + 4 * w + b_] = o0 * inv;
            outs[(1 * 4 + a_) * 1028 + 4 * w + b_] = o1 * inv;
        }
    }
    __syncthreads();

    // coalesced copy-out: 8192 dwords, stride-1 per 256-thread group
    const int H4 = 4 * HH, W4 = 4 * WW;
    #pragma unroll
    for (int it = 0; it < 32; ++it) {
        const int i = it * 256 + tid;
        const int w4 = i & 1023, a = (i >> 10) & 3, c = i >> 12;
        out[(((size_t)(n * 2 + c)) * H4 + 4 * h + a) * W4 + w4] =
            outs[(c * 4 + a) * 1028 + w4];
    }
}

// ---------------------------------------------------------------------------
extern "C" void kernel_launch(void* const* d_in, const int* in_sizes, int n_in,
                              void* d_out, int out_size, void* d_ws, size_t ws_size,
                              hipStream_t stream)
{
    const float* flow = (const float*)d_in[0];
    const float* feat = (const float*)d_in[1];
    const float* w1   = (const float*)d_in[2];
    const float* b1   = (const float*)d_in[3];
    const float* w2   = (const float*)d_in[4];
    const float* b2   = (const float*)d_in[5];
    float* out = (float*)d_out;

    short* featT = (short*)d_ws;
    short* hfeat = featT + (size_t)3 * NPX * 32;         // 12,582,912
    short* w1p   = hfeat + (size_t)4 * NPX * 32;         // 16,777,216
    short* w2p   = w1p + (size_t)3 * 9 * 8 * 512;        // 110,592
    short* zbuf  = w2p + (size_t)4 * 9 * 9 * 512;        // 165,888 (16B-aligned)

    // blocks: 512 transpose + 432 pack-w1 + 648 pack-w2 = 1592
    prolog<<<1592, 256, 0, stream>>>(feat, featT, zbuf, w1, w1p, w2, w2p);
    conv1_mfma<<<NN * HH, 256, 0, stream>>>(featT, w1p, b1, hfeat, zbuf);
    conv2_fused<<<NN * HH, 256, 0, stream>>>(hfeat, w2p, b2, flow, out, zbuf);
}

// Round 10
// 175.632 us; speedup vs baseline: 1.0166x; 1.0166x over previous
//
#include <hip/hip_runtime.h>
#include <hip/hip_bf16.h>

#define NN  4
#define CIN 96
#define C1  128
#define C2  144
#define HH  128
#define WW  256
#define NPX ((size_t)NN * HH * WW)          // pixels per chunk-plane (131072)

typedef short bf16x8 __attribute__((ext_vector_type(8)));
typedef float f32x4  __attribute__((ext_vector_type(4)));
typedef unsigned int u32x4 __attribute__((ext_vector_type(4)));

__device__ __forceinline__ short f2bs(float v) {
    __hip_bfloat16 b = __float2bfloat16(v);
    short s; __builtin_memcpy(&s, &b, 2); return s;
}

// async global->LDS, 16B per lane. LDS dest linear (base + lane*16).
__device__ __forceinline__ void gld16(const void* g, void* l) {
    __builtin_amdgcn_global_load_lds(
        (const __attribute__((address_space(1))) void*)g,
        (__attribute__((address_space(3))) void*)l, 16, 0, 0);
}

// ---------------------------------------------------------------------------
// Fused prolog: blocks [0,512) transpose feat NCHW fp32 -> chunk-major bf16
// featT[kc][n][h][w][32]; blocks [512,944) pack w1; blocks [944,1592) pack w2.
__global__ __launch_bounds__(256) void prolog(
    const float* __restrict__ feat, short* __restrict__ featT,
    short* __restrict__ zbuf,
    const float* __restrict__ w1, short* __restrict__ w1p,
    const float* __restrict__ w2, short* __restrict__ w2p)
{
    __shared__ unsigned int lds[48 * 258];        // 49.5 KB (transpose blocks only)
    const int b   = blockIdx.x;
    const int tid = threadIdx.x;

    if (b < 512) {                                // ---- transpose ----
        const int h = b & (HH - 1);
        const int n = b >> 7;
        if (b == 0 && tid < 32) zbuf[tid] = 0;

        #pragma unroll 4
        for (int cp = 0; cp < 48; ++cp) {         // channel pairs
            float v0 = feat[(((size_t)n * CIN + 2 * cp    ) * HH + h) * WW + tid];
            float v1 = feat[(((size_t)n * CIN + 2 * cp + 1) * HH + h) * WW + tid];
            unsigned int p = (unsigned int)(unsigned short)f2bs(v0)
                           | ((unsigned int)(unsigned short)f2bs(v1) << 16);
            lds[cp * 258 + tid] = p;
        }
        __syncthreads();
        const size_t rowbase = (size_t)(n * HH + h) * WW * 32;
        #pragma unroll
        for (int kc = 0; kc < 3; ++kc) {
            short* dst = featT + (size_t)kc * (NPX * 32) + rowbase;
            #pragma unroll
            for (int it = 0; it < 4; ++it) {
                const int slot = it * 256 + tid;
                const int px = slot >> 2, sub = slot & 3;
                u32x4 v;                           // ci pairs kc*16+sub*4+k
                #pragma unroll
                for (int k = 0; k < 4; ++k)
                    v[k] = lds[(kc * 16 + sub * 4 + k) * 258 + px];
                *(u32x4*)&dst[(size_t)slot * 8] = v;
            }
        }
        return;
    }

    // ---- weight packs: wp[(((kci*9+tap)*nct+ct)*64+lane)*8+j] ----
    const float* w; short* wp; int cin, nct, i;
    if (b < 944) { w = w1; wp = w1p; cin = CIN; nct = 8; i = (b - 512) * 256 + tid; }
    else         { w = w2; wp = w2p; cin = C1;  nct = 9; i = (b - 944) * 256 + tid; }
    const int j    = i & 7;
    const int col  = (i >> 3) & 15;
    const int quad = (i >> 7) & 3;
    int t = i >> 9;                               // (kci*9+tap)*nct + ct
    const int ct  = t % nct;  t /= nct;
    const int tap = t % 9;
    const int kci = t / 9;
    const int co = ct * 16 + col;
    const int ci = kci * 32 + quad * 8 + j;
    wp[i] = f2bs(w[((size_t)co * cin + ci) * 9 + tap]);
}

// ---------------------------------------------------------------------------
// conv1, big-interval structure: 2-row blocks (grid 256 = 1/CU), 512 thr /
// 8 waves; wave = (row wr, 64-px strip), mt=4 (r6's proven per-wave codegen).
// Per K-chunk: stage 4-row A tile (66 KB) + full-chunk B (73.7 KB) -> ONE
// barrier pair, then 27 taps of pure-LDS compute (324 MFMA/wave) with no
// intervening syncs. Barriers: 24 -> 5.
__global__ __launch_bounds__(512, 2) void conv1_mfma(
    const short* __restrict__ featT, const short* __restrict__ w1p,
    const float* __restrict__ b1, short* __restrict__ hfeat,
    const short* __restrict__ zbuf)
{
    __shared__ __attribute__((aligned(16))) short ldsA[4 * 258 * 32]; // 66,048 B
    __shared__ __attribute__((aligned(16))) short ldsB[9 * 8 * 512];  // 73,728 B
    const int tid  = threadIdx.x;
    const int bid  = ((blockIdx.x & 7) << 5) + (blockIdx.x >> 3); // 256 = 8x32
    const int h0   = (bid & 63) * 2;
    const int n    = bid >> 6;
    const int lane = tid & 63, wave = tid >> 6;
    const int quad = lane >> 4, col = lane & 15;
    const int wr   = wave >> 2;                   // output row within pair
    const int wp0  = (wave & 3) * 64;             // 64-px strip

    f32x4 acc[4][8];
    #pragma unroll
    for (int mt = 0; mt < 4; ++mt)
        #pragma unroll
        for (int ct = 0; ct < 8; ++ct)
            #pragma unroll
            for (int r = 0; r < 4; ++r) acc[mt][ct][r] = 0.f;

    auto stageA = [&](int kci) {                  // 4 halo rows, 4128 slots
        const short* cbase = featT + (size_t)kci * (NPX * 32);
        for (int s = tid; s < 4 * 258 * 4; s += 512) {
            const int cig = s & 3;
            const int px  = (s >> 2) % 258;
            const int row = (s >> 2) / 258;
            const int hh = h0 + row - 1, gw = px - 1;
            const short* g = zbuf;
            if (hh >= 0 && hh < HH && gw >= 0 && gw < WW)
                g = cbase + ((size_t)(n * HH + hh) * WW + gw) * 32
                    + ((cig ^ ((px >> 1) & 3)) << 3);   // source pre-swizzle
            gld16(g, &ldsA[s * 8]);
        }
    };
    auto stageB = [&](int kci) {                  // full chunk: 4608 x 16B
        const short* gB = w1p + (size_t)kci * (9 * 8 * 512);
        for (int s = tid; s < 4608; s += 512)
            gld16(gB + s * 8, &ldsB[s * 8]);
    };
    auto compute3 = [&](int tg) {                 // 3 taps, dh = tg
        #pragma unroll
        for (int dw = 0; dw < 3; ++dw) {
            bf16x8 af[4];
            #pragma unroll
            for (int mt = 0; mt < 4; ++mt) {
                const int px = wp0 + mt * 16 + col + dw;
                const int slot = ((wr + tg) * 258 + px) * 4 + (quad ^ ((px >> 1) & 3));
                af[mt] = *(const bf16x8*)&ldsA[slot * 8];
            }
            #pragma unroll
            for (int ct = 0; ct < 8; ++ct) {
                const bf16x8 bfr = *(const bf16x8*)
                    &ldsB[(((tg * 3 + dw) * 8 + ct) << 9) + (lane << 3)];
                #pragma unroll
                for (int mt = 0; mt < 4; ++mt)
                    acc[mt][ct] = __builtin_amdgcn_mfma_f32_16x16x32_bf16(af[mt], bfr, acc[mt][ct], 0, 0, 0);
            }
        }
    };

    stageA(0);
    stageB(0);
    __syncthreads();
    for (int kci = 0; kci < 3; ++kci) {
        compute3(0); compute3(1); compute3(2);    // 324 MFMA/wave, no syncs
        if (kci == 2) break;
        __syncthreads();                          // all done reading A/B
        stageA(kci + 1);
        stageB(kci + 1);
        __syncthreads();                          // drain
    }

    float bias[8];
    #pragma unroll
    for (int ct = 0; ct < 8; ++ct) bias[ct] = b1[ct * 16 + col];
    const int h = h0 + wr;
    #pragma unroll
    for (int mt = 0; mt < 4; ++mt)
        #pragma unroll
        for (int r = 0; r < 4; ++r) {
            const int w = wp0 + mt * 16 + quad * 4 + r;
            const size_t pxw = (size_t)(n * HH + h) * WW + w;
            #pragma unroll
            for (int ct = 0; ct < 8; ++ct) {
                float a = acc[mt][ct][r] + bias[ct];
                a = a > 0.f ? a : 0.1f * a;       // LeakyReLU(0.1)
                hfeat[((size_t)(ct >> 1) * NPX + pxw) * 32 + (ct & 1) * 16 + col] = f2bs(a);
            }
        }
}

// ---------------------------------------------------------------------------
// conv2 + fused epilogue, big-interval structure: 4 K-chunks, full-chunk B
// (82.9 KB) + 4-row A (66 KB) = 149 KB LDS, 7 barriers total. Epilogue:
// 2-row LDS out-stage in ldsA (fully coalesced copy-out), flow cache in ldsB.
__global__ __launch_bounds__(512, 2) void conv2_fused(
    const short* __restrict__ hfeat, const short* __restrict__ w2p,
    const float* __restrict__ b2, const float* __restrict__ flow,
    float* __restrict__ out, const short* __restrict__ zbuf)
{
    __shared__ __attribute__((aligned(16))) short ldsA[4 * 258 * 32]; // 66,048 B
    __shared__ __attribute__((aligned(16))) short ldsB[9 * 9 * 512];  // 82,944 B
    const int tid  = threadIdx.x;
    const int bid  = ((blockIdx.x & 7) << 5) + (blockIdx.x >> 3);
    const int h0   = (bid & 63) * 2;
    const int n    = bid >> 6;
    const int lane = tid & 63, wave = tid >> 6;
    const int quad = lane >> 4, col = lane & 15;
    const int wr   = wave >> 2;
    const int wp0  = (wave & 3) * 64;

    f32x4 acc[4][9];
    #pragma unroll
    for (int mt = 0; mt < 4; ++mt)
        #pragma unroll
        for (int ct = 0; ct < 9; ++ct)
            #pragma unroll
            for (int r = 0; r < 4; ++r) acc[mt][ct][r] = 0.f;

    auto stageA = [&](int kci) {
        const short* cbase = hfeat + (size_t)kci * (NPX * 32);
        for (int s = tid; s < 4 * 258 * 4; s += 512) {
            const int cig = s & 3;
            const int px  = (s >> 2) % 258;
            const int row = (s >> 2) / 258;
            const int hh = h0 + row - 1, gw = px - 1;
            const short* g = zbuf;
            if (hh >= 0 && hh < HH && gw >= 0 && gw < WW)
                g = cbase + ((size_t)(n * HH + hh) * WW + gw) * 32
                    + ((cig ^ ((px >> 1) & 3)) << 3);
            gld16(g, &ldsA[s * 8]);
        }
    };
    auto stageB = [&](int kci) {                  // full chunk: 5184 x 16B
        const short* gB = w2p + (size_t)kci * (9 * 9 * 512);
        for (int s = tid; s < 5184; s += 512)
            gld16(gB + s * 8, &ldsB[s * 8]);
    };
    auto compute3 = [&](int tg) {
        #pragma unroll
        for (int dw = 0; dw < 3; ++dw) {
            bf16x8 af[4];
            #pragma unroll
            for (int mt = 0; mt < 4; ++mt) {
                const int px = wp0 + mt * 16 + col + dw;
                const int slot = ((wr + tg) * 258 + px) * 4 + (quad ^ ((px >> 1) & 3));
                af[mt] = *(const bf16x8*)&ldsA[slot * 8];
            }
            #pragma unroll
            for (int ct = 0; ct < 9; ++ct) {
                const bf16x8 bfr = *(const bf16x8*)
                    &ldsB[(((tg * 3 + dw) * 9 + ct) << 9) + (lane << 3)];
                #pragma unroll
                for (int mt = 0; mt < 4; ++mt)
                    acc[mt][ct] = __builtin_amdgcn_mfma_f32_16x16x32_bf16(af[mt], bfr, acc[mt][ct], 0, 0, 0);
            }
        }
    };

    stageA(0);
    stageB(0);
    __syncthreads();
    for (int kci = 0; kci < 4; ++kci) {
        compute3(0); compute3(1); compute3(2);
        if (kci == 3) break;
        __syncthreads();
        stageA(kci + 1);
        stageB(kci + 1);
        __syncthreads();
    }
    __syncthreads();                              // epilogue boundary

    // ---- epilogue: ldsA = out-stage [2][2][4][1028]; ldsB = flow cache ----
    float* outs = (float*)ldsA;                   // 65,792 B <= 66,048 ✓
    float* flds = (float*)ldsB;                   // [2][4][264] = 8,448 B
    for (int i = tid; i < 2 * 4 * 258; i += 512) {
        const int px = i % 258;
        const int t  = i / 258;
        const int row = t & 3, c = t >> 2;
        const int hh = h0 + row - 1, gw = px - 1;
        float v = 0.f;
        if (hh >= 0 && hh < HH && gw >= 0 && gw < WW)
            v = flow[(((size_t)n * 2 + c) * HH + hh) * WW + gw];
        flds[(c * 4 + row) * 264 + px] = v;
    }
    __syncthreads();

    const int a_ = col >> 2, b_ = col & 3;
    float bias[9];
    #pragma unroll
    for (int k = 0; k < 9; ++k) bias[k] = b2[k * 16 + col];

    #pragma unroll
    for (int mt = 0; mt < 4; ++mt) {
        const int w0 = wp0 + mt * 16 + quad * 4;
        float fw[2][3][6];                        // flow window w0-1 .. w0+4
        #pragma unroll
        for (int c = 0; c < 2; ++c)
            #pragma unroll
            for (int ki = 0; ki < 3; ++ki)
                #pragma unroll
                for (int j = 0; j < 6; ++j)
                    fw[c][ki][j] = flds[(c * 4 + wr + ki) * 264 + w0 + j];
        #pragma unroll
        for (int r = 0; r < 4; ++r) {
            const int w = w0 + r;
            float v[9], mx = -1e30f;
            #pragma unroll
            for (int k = 0; k < 9; ++k) {
                v[k] = 0.25f * (acc[mt][k][r] + bias[k]);
                mx = fmaxf(mx, v[k]);
            }
            float s = 0.f;
            #pragma unroll
            for (int k = 0; k < 9; ++k) { v[k] = __expf(v[k] - mx); s += v[k]; }
            const float inv = 4.f / s;            // folds the 4*flow scale
            float o0 = 0.f, o1 = 0.f;
            #pragma unroll
            for (int ki = 0; ki < 3; ++ki)
                #pragma unroll
                for (int kj = 0; kj < 3; ++kj) {
                    const float wgt = v[ki * 3 + kj];
                    o0 += wgt * fw[0][ki][r + kj];
                    o1 += wgt * fw[1][ki][r + kj];
                }
            outs[((0 * 2 + wr) * 4 + a_) * 1028 + 4 * w + b_] = o0 * inv;
            outs[((1 * 2 + wr) * 4 + a_) * 1028 + 4 * w + b_] = o1 * inv;
        }
    }
    __syncthreads();

    // coalesced copy-out: 16384 dwords, stride-1 per 512-thread group
    const int H4 = 4 * HH, W4 = 4 * WW;
    #pragma unroll
    for (int it = 0; it < 32; ++it) {
        const int i = it * 512 + tid;
        const int w4 = i & 1023, a = (i >> 10) & 3, rw = (i >> 12) & 1, c = i >> 13;
        out[(((size_t)(n * 2 + c)) * H4 + 4 * (h0 + rw) + a) * W4 + w4] =
            outs[((c * 2 + rw) * 4 + a) * 1028 + w4];
    }
}

// ---------------------------------------------------------------------------
extern "C" void kernel_launch(void* const* d_in, const int* in_sizes, int n_in,
                              void* d_out, int out_size, void* d_ws, size_t ws_size,
                              hipStream_t stream)
{
    const float* flow = (const float*)d_in[0];
    const float* feat = (const float*)d_in[1];
    const float* w1   = (const float*)d_in[2];
    const float* b1   = (const float*)d_in[3];
    const float* w2   = (const float*)d_in[4];
    const float* b2   = (const float*)d_in[5];
    float* out = (float*)d_out;

    short* featT = (short*)d_ws;
    short* hfeat = featT + (size_t)3 * NPX * 32;         // 12,582,912
    short* w1p   = hfeat + (size_t)4 * NPX * 32;         // 16,777,216
    short* w2p   = w1p + (size_t)3 * 9 * 8 * 512;        // 110,592
    short* zbuf  = w2p + (size_t)4 * 9 * 9 * 512;        // 165,888 (16B-aligned)

    // blocks: 512 transpose + 432 pack-w1 + 648 pack-w2 = 1592
    prolog<<<1592, 256, 0, stream>>>(feat, featT, zbuf, w1, w1p, w2, w2p);
    conv1_mfma<<<NN * HH / 2, 512, 0, stream>>>(featT, w1p, b1, hfeat, zbuf);
    conv2_fused<<<NN * HH / 2, 512, 0, stream>>>(hfeat, w2p, b2, flow, out, zbuf);
}

// Round 11
// 172.859 us; speedup vs baseline: 1.0329x; 1.0160x over previous
//
#include <hip/hip_runtime.h>
#include <hip/hip_bf16.h>

#define NN  4
#define CIN 96
#define C1  128
#define C2  144
#define HH  128
#define WW  256
#define NPX ((size_t)NN * HH * WW)          // pixels per chunk-plane (131072)

typedef short bf16x8 __attribute__((ext_vector_type(8)));
typedef float f32x4  __attribute__((ext_vector_type(4)));
typedef unsigned int u32x4 __attribute__((ext_vector_type(4)));

__device__ __forceinline__ short f2bs(float v) {
    __hip_bfloat16 b = __float2bfloat16(v);
    short s; __builtin_memcpy(&s, &b, 2); return s;
}

// async global->LDS, 16B per lane. LDS dest linear (base + lane*16).
__device__ __forceinline__ void gld16(const void* g, void* l) {
    __builtin_amdgcn_global_load_lds(
        (const __attribute__((address_space(1))) void*)g,
        (__attribute__((address_space(3))) void*)l, 16, 0, 0);
}

// ---------------------------------------------------------------------------
// Fused prolog: blocks [0,512) transpose feat NCHW fp32 -> chunk-major bf16
// featT[kc][n][h][w][32]; blocks [512,944) pack w1; blocks [944,1592) pack w2.
__global__ __launch_bounds__(256) void prolog(
    const float* __restrict__ feat, short* __restrict__ featT,
    short* __restrict__ zbuf,
    const float* __restrict__ w1, short* __restrict__ w1p,
    const float* __restrict__ w2, short* __restrict__ w2p)
{
    __shared__ unsigned int lds[48 * 258];        // 49.5 KB (transpose blocks only)
    const int b   = blockIdx.x;
    const int tid = threadIdx.x;

    if (b < 512) {                                // ---- transpose ----
        const int h = b & (HH - 1);
        const int n = b >> 7;
        if (b == 0 && tid < 32) zbuf[tid] = 0;

        #pragma unroll 4
        for (int cp = 0; cp < 48; ++cp) {         // channel pairs
            float v0 = feat[(((size_t)n * CIN + 2 * cp    ) * HH + h) * WW + tid];
            float v1 = feat[(((size_t)n * CIN + 2 * cp + 1) * HH + h) * WW + tid];
            unsigned int p = (unsigned int)(unsigned short)f2bs(v0)
                           | ((unsigned int)(unsigned short)f2bs(v1) << 16);
            lds[cp * 258 + tid] = p;
        }
        __syncthreads();
        const size_t rowbase = (size_t)(n * HH + h) * WW * 32;
        #pragma unroll
        for (int kc = 0; kc < 3; ++kc) {
            short* dst = featT + (size_t)kc * (NPX * 32) + rowbase;
            #pragma unroll
            for (int it = 0; it < 4; ++it) {
                const int slot = it * 256 + tid;
                const int px = slot >> 2, sub = slot & 3;
                u32x4 v;                           // ci pairs kc*16+sub*4+k
                #pragma unroll
                for (int k = 0; k < 4; ++k)
                    v[k] = lds[(kc * 16 + sub * 4 + k) * 258 + px];
                *(u32x4*)&dst[(size_t)slot * 8] = v;
            }
        }
        return;
    }

    // ---- weight packs: wp[(((kci*9+tap)*nct+ct)*64+lane)*8+j] ----
    const float* w; short* wp; int cin, nct, i;
    if (b < 944) { w = w1; wp = w1p; cin = CIN; nct = 8; i = (b - 512) * 256 + tid; }
    else         { w = w2; wp = w2p; cin = C1;  nct = 9; i = (b - 944) * 256 + tid; }
    const int j    = i & 7;
    const int col  = (i >> 3) & 15;
    const int quad = (i >> 7) & 3;
    int t = i >> 9;                               // (kci*9+tap)*nct + ct
    const int ct  = t % nct;  t /= nct;
    const int tap = t % 9;
    const int kci = t / 9;
    const int co = ct * 16 + col;
    const int ci = kci * 32 + quad * 8 + j;
    wp[i] = f2bs(w[((size_t)co * cin + ci) * 9 + tap]);
}

// ---------------------------------------------------------------------------
// conv1 (r10 champion): big-interval. 2-row blocks (grid 256 = 1/CU), 512
// thr / 8 waves; wave = (row, 64-px strip), mt=4, ct=8 -> 248 regs (fits
// 2 waves/SIMD, no spill). Per K-chunk: stage 4-row A (66 KB) + full-chunk
// B (73.7 KB), one barrier pair, then 27 taps pure-LDS compute. 5 barriers.
__global__ __launch_bounds__(512, 2) void conv1_mfma(
    const short* __restrict__ featT, const short* __restrict__ w1p,
    const float* __restrict__ b1, short* __restrict__ hfeat,
    const short* __restrict__ zbuf)
{
    __shared__ __attribute__((aligned(16))) short ldsA[4 * 258 * 32]; // 66,048 B
    __shared__ __attribute__((aligned(16))) short ldsB[9 * 8 * 512];  // 73,728 B
    const int tid  = threadIdx.x;
    const int bid  = ((blockIdx.x & 7) << 5) + (blockIdx.x >> 3); // 256 = 8x32
    const int h0   = (bid & 63) * 2;
    const int n    = bid >> 6;
    const int lane = tid & 63, wave = tid >> 6;
    const int quad = lane >> 4, col = lane & 15;
    const int wr   = wave >> 2;                   // output row within pair
    const int wp0  = (wave & 3) * 64;             // 64-px strip

    f32x4 acc[4][8];
    #pragma unroll
    for (int mt = 0; mt < 4; ++mt)
        #pragma unroll
        for (int ct = 0; ct < 8; ++ct)
            #pragma unroll
            for (int r = 0; r < 4; ++r) acc[mt][ct][r] = 0.f;

    auto stageA = [&](int kci) {                  // 4 halo rows, 4128 slots
        const short* cbase = featT + (size_t)kci * (NPX * 32);
        for (int s = tid; s < 4 * 258 * 4; s += 512) {
            const int cig = s & 3;
            const int px  = (s >> 2) % 258;
            const int row = (s >> 2) / 258;
            const int hh = h0 + row - 1, gw = px - 1;
            const short* g = zbuf;
            if (hh >= 0 && hh < HH && gw >= 0 && gw < WW)
                g = cbase + ((size_t)(n * HH + hh) * WW + gw) * 32
                    + ((cig ^ ((px >> 1) & 3)) << 3);   // source pre-swizzle
            gld16(g, &ldsA[s * 8]);
        }
    };
    auto stageB = [&](int kci) {                  // full chunk: 4608 x 16B
        const short* gB = w1p + (size_t)kci * (9 * 8 * 512);
        for (int s = tid; s < 4608; s += 512)
            gld16(gB + s * 8, &ldsB[s * 8]);
    };
    auto compute3 = [&](int tg) {                 // 3 taps, dh = tg
        #pragma unroll
        for (int dw = 0; dw < 3; ++dw) {
            bf16x8 af[4];
            #pragma unroll
            for (int mt = 0; mt < 4; ++mt) {
                const int px = wp0 + mt * 16 + col + dw;
                const int slot = ((wr + tg) * 258 + px) * 4 + (quad ^ ((px >> 1) & 3));
                af[mt] = *(const bf16x8*)&ldsA[slot * 8];
            }
            #pragma unroll
            for (int ct = 0; ct < 8; ++ct) {
                const bf16x8 bfr = *(const bf16x8*)
                    &ldsB[(((tg * 3 + dw) * 8 + ct) << 9) + (lane << 3)];
                #pragma unroll
                for (int mt = 0; mt < 4; ++mt)
                    acc[mt][ct] = __builtin_amdgcn_mfma_f32_16x16x32_bf16(af[mt], bfr, acc[mt][ct], 0, 0, 0);
            }
        }
    };

    stageA(0);
    stageB(0);
    __syncthreads();
    for (int kci = 0; kci < 3; ++kci) {
        compute3(0); compute3(1); compute3(2);    // 324 MFMA/wave, no syncs
        if (kci == 2) break;
        __syncthreads();                          // all done reading A/B
        stageA(kci + 1);
        stageB(kci + 1);
        __syncthreads();                          // drain
    }

    float bias[8];
    #pragma unroll
    for (int ct = 0; ct < 8; ++ct) bias[ct] = b1[ct * 16 + col];
    const int h = h0 + wr;
    #pragma unroll
    for (int mt = 0; mt < 4; ++mt)
        #pragma unroll
        for (int r = 0; r < 4; ++r) {
            const int w = wp0 + mt * 16 + quad * 4 + r;
            const size_t pxw = (size_t)(n * HH + h) * WW + w;
            #pragma unroll
            for (int ct = 0; ct < 8; ++ct) {
                float a = acc[mt][ct][r] + bias[ct];
                a = a > 0.f ? a : 0.1f * a;       // LeakyReLU(0.1)
                hfeat[((size_t)(ct >> 1) * NPX + pxw) * 32 + (ct & 1) * 16 + col] = f2bs(a);
            }
        }
}

// ---------------------------------------------------------------------------
// conv2 (r6 champion): 1-row blocks, 256 thr / 4 waves (wave = 64-px strip,
// mt=4), grid 512 = 2 blocks/CU (LDS 77.2 KB; 104 VGPR + 144 acc = 248 regs,
// no spill). A single-buffered (XOR-swizzled via source), B per 3-tap group.
// Stage drains covered by the co-resident block. Epilogue: LDS out-stage
// (stride 1028) -> fully coalesced copy-out.
__global__ __launch_bounds__(256, 2) void conv2_fused(
    const short* __restrict__ hfeat, const short* __restrict__ w2p,
    const float* __restrict__ b2, const float* __restrict__ flow,
    float* __restrict__ out, const short* __restrict__ zbuf)
{
    __shared__ __attribute__((aligned(16))) short ldsA[3 * 258 * 32];   // 49,536 B
    __shared__ __attribute__((aligned(16))) short ldsB[3 * 9 * 512];    // 27,648 B
    const int tid  = threadIdx.x;
    const int bid  = ((blockIdx.x & 7) << 6) + (blockIdx.x >> 3);  // 512 = 8x64
    const int h    = bid & (HH - 1);
    const int n    = bid >> 7;
    const int lane = tid & 63, wave = tid >> 6;
    const int quad = lane >> 4, col = lane & 15;
    const int wp0  = wave * 64;

    f32x4 acc[4][9];
    #pragma unroll
    for (int mt = 0; mt < 4; ++mt)
        #pragma unroll
        for (int ct = 0; ct < 9; ++ct)
            #pragma unroll
            for (int r = 0; r < 4; ++r) acc[mt][ct][r] = 0.f;

    auto stageA = [&](int kci) {
        const short* cbase = hfeat + (size_t)kci * (NPX * 32);
        for (int s = tid; s < 3 * 258 * 4; s += 256) {
            const int cig = s & 3;
            const int px  = (s >> 2) % 258;
            const int row = (s >> 2) / 258;
            const int hh = h + row - 1, gw = px - 1;
            const short* g = zbuf;
            if (hh >= 0 && hh < HH && gw >= 0 && gw < WW)
                g = cbase + ((size_t)(n * HH + hh) * WW + gw) * 32
                    + ((cig ^ ((px >> 1) & 3)) << 3);
            gld16(g, &ldsA[s * 8]);
        }
    };
    auto stageB = [&](int kci, int tg) {
        const short* gB = w2p + (((size_t)(kci * 9 + tg * 3) * 9) << 9);
        for (int t = tid; t < 3 * 9 * 64; t += 256)     // 1728 x 16B contiguous
            gld16(gB + t * 8, &ldsB[t * 8]);
    };
    auto compute = [&](int tg) {
        #pragma unroll
        for (int dw = 0; dw < 3; ++dw) {
            bf16x8 af[4];
            #pragma unroll
            for (int mt = 0; mt < 4; ++mt) {
                const int px = wp0 + mt * 16 + col + dw;
                const int slot = (tg * 258 + px) * 4 + (quad ^ ((px >> 1) & 3));
                af[mt] = *(const bf16x8*)&ldsA[slot * 8];
            }
            #pragma unroll
            for (int ct = 0; ct < 9; ++ct) {
                const bf16x8 bfr = *(const bf16x8*)&ldsB[((dw * 9 + ct) << 9) + (lane << 3)];
                #pragma unroll
                for (int mt = 0; mt < 4; ++mt)
                    acc[mt][ct] = __builtin_amdgcn_mfma_f32_16x16x32_bf16(af[mt], bfr, acc[mt][ct], 0, 0, 0);
            }
        }
    };

    stageA(0);
    stageB(0, 0);
    __syncthreads();
    for (int kci = 0; kci < 4; ++kci)
        for (int tg = 0; tg < 3; ++tg) {
            compute(tg);
            __syncthreads();
            if (!(kci == 3 && tg == 2)) {
                int nk = kci, ntg = tg + 1;
                if (ntg == 3) { nk = kci + 1; ntg = 0; }
                if (ntg == 0) stageA(nk);
                stageB(nk, ntg);
                __syncthreads();
            }
        }

    // ---- epilogue: ldsA reused as out-stage [2][4][1028] + flow cache ----
    float* outs = (float*)ldsA;                   // 32,896 B
    float* flds = (float*)ldsA + 8224;            // [2][3][264], 6,336 B
    for (int i = tid; i < 2 * 3 * 258; i += 256) {
        const int px = i % 258;
        const int t  = i / 258;
        const int row = t % 3, c = t / 3;
        const int hh = h + row - 1, gw = px - 1;
        float v = 0.f;
        if (hh >= 0 && hh < HH && gw >= 0 && gw < WW)
            v = flow[(((size_t)n * 2 + c) * HH + hh) * WW + gw];
        flds[(c * 3 + row) * 264 + px] = v;
    }
    __syncthreads();

    const int a_ = col >> 2, b_ = col & 3;
    float bias[9];
    #pragma unroll
    for (int k = 0; k < 9; ++k) bias[k] = b2[k * 16 + col];

    #pragma unroll
    for (int mt = 0; mt < 4; ++mt) {
        const int w0 = wp0 + mt * 16 + quad * 4;
        float fw[2][3][6];                        // flow window w0-1 .. w0+4
        #pragma unroll
        for (int c = 0; c < 2; ++c)
            #pragma unroll
            for (int ki = 0; ki < 3; ++ki)
                #pragma unroll
                for (int j = 0; j < 6; ++j)
                    fw[c][ki][j] = flds[(c * 3 + ki) * 264 + w0 + j];
        #pragma unroll
        for (int r = 0; r < 4; ++r) {
            const int w = w0 + r;
            float v[9], mx = -1e30f;
            #pragma unroll
            for (int k = 0; k < 9; ++k) {
                v[k] = 0.25f * (acc[mt][k][r] + bias[k]);
                mx = fmaxf(mx, v[k]);
            }
            float s = 0.f;
            #pragma unroll
            for (int k = 0; k < 9; ++k) { v[k] = __expf(v[k] - mx); s += v[k]; }
            const float inv = 4.f / s;            // folds the 4*flow scale
            float o0 = 0.f, o1 = 0.f;
            #pragma unroll
            for (int ki = 0; ki < 3; ++ki)
                #pragma unroll
                for (int kj = 0; kj < 3; ++kj) {
                    const float wgt = v[ki * 3 + kj];
                    o0 += wgt * fw[0][ki][r + kj];
                    o1 += wgt * fw[1][ki][r + kj];
                }
            outs[(0 * 4 + a_) * 1028 + 4 * w + b_] = o0 * inv;
            outs[(1 * 4 + a_) * 1028 + 4 * w + b_] = o1 * inv;
        }
    }
    __syncthreads();

    // coalesced copy-out: 8192 dwords, stride-1 per 256-thread group
    const int H4 = 4 * HH, W4 = 4 * WW;
    #pragma unroll
    for (int it = 0; it < 32; ++it) {
        const int i = it * 256 + tid;
        const int w4 = i & 1023, a = (i >> 10) & 3, c = i >> 12;
        out[(((size_t)(n * 2 + c)) * H4 + 4 * h + a) * W4 + w4] =
            outs[(c * 4 + a) * 1028 + w4];
    }
}

// ---------------------------------------------------------------------------
extern "C" void kernel_launch(void* const* d_in, const int* in_sizes, int n_in,
                              void* d_out, int out_size, void* d_ws, size_t ws_size,
                              hipStream_t stream)
{
    const float* flow = (const float*)d_in[0];
    const float* feat = (const float*)d_in[1];
    const float* w1   = (const float*)d_in[2];
    const float* b1   = (const float*)d_in[3];
    const float* w2   = (const float*)d_in[4];
    const float* b2   = (const float*)d_in[5];
    float* out = (float*)d_out;

    short* featT = (short*)d_ws;
    short* hfeat = featT + (size_t)3 * NPX * 32;         // 12,582,912
    short* w1p   = hfeat + (size_t)4 * NPX * 32;         // 16,777,216
    short* w2p   = w1p + (size_t)3 * 9 * 8 * 512;        // 110,592
    short* zbuf  = w2p + (size_t)4 * 9 * 9 * 512;        // 165,888 (16B-aligned)

    // blocks: 512 transpose + 432 pack-w1 + 648 pack-w2 = 1592
    prolog<<<1592, 256, 0, stream>>>(feat, featT, zbuf, w1, w1p, w2, w2p);
    conv1_mfma<<<NN * HH / 2, 512, 0, stream>>>(featT, w1p, b1, hfeat, zbuf);
    conv2_fused<<<NN * HH, 256, 0, stream>>>(hfeat, w2p, b2, flow, out, zbuf);
}